// Round 6
// baseline (256.549 us; speedup 1.0000x reference)
//
#include <hip/hip_runtime.h>

#define NROWS 131072          // 64*2048
#define D 64
#define K 512
#define TPB 256
#define NBLOCKS (NROWS/TPB)   // 512 blocks = 2 blocks/CU = 8 waves/CU

#define LOSS_OFF (NROWS*D)    // 8388608
#define PERP_OFF (LOSS_OFF+1)
#define IDX_OFF  (LOSS_OFF+2)

typedef float f32x16 __attribute__((ext_vector_type(16)));

// ws layout: [0]: float wsum; [256B]: int hist[512]; [4096B]: float e2[512]

__global__ __launch_bounds__(64) void vq_norms(
    const float* __restrict__ emb, float* __restrict__ e2)
{
    int k = blockIdx.x * 64 + threadIdx.x;   // grid 8 x 64
    const float* e = emb + (size_t)k * D;
    float s0=0.f,s1=0.f,s2=0.f,s3=0.f;
    #pragma unroll
    for (int d = 0; d < D; d += 4) {
        s0 = fmaf(e[d+0], e[d+0], s0);
        s1 = fmaf(e[d+1], e[d+1], s1);
        s2 = fmaf(e[d+2], e[d+2], s2);
        s3 = fmaf(e[d+3], e[d+3], s3);
    }
    e2[k] = (s0+s1)+(s2+s3);   // same order as rounds 1-5 (absmax 0.0)
}

// accumulate 16 elements of buf CV (d = DBASE..DBASE+15) into chains a0..a3,
// element order d ascending, chain = d%4 — bit-identical sequence to R1-R5.
#define ACCBUF(CV, DBASE)                                \
    a0 = fmaf(xr[(DBASE)+ 0], (CV)[ 0], a0);             \
    a1 = fmaf(xr[(DBASE)+ 1], (CV)[ 1], a1);             \
    a2 = fmaf(xr[(DBASE)+ 2], (CV)[ 2], a2);             \
    a3 = fmaf(xr[(DBASE)+ 3], (CV)[ 3], a3);             \
    a0 = fmaf(xr[(DBASE)+ 4], (CV)[ 4], a0);             \
    a1 = fmaf(xr[(DBASE)+ 5], (CV)[ 5], a1);             \
    a2 = fmaf(xr[(DBASE)+ 6], (CV)[ 6], a2);             \
    a3 = fmaf(xr[(DBASE)+ 7], (CV)[ 7], a3);             \
    a0 = fmaf(xr[(DBASE)+ 8], (CV)[ 8], a0);             \
    a1 = fmaf(xr[(DBASE)+ 9], (CV)[ 9], a1);             \
    a2 = fmaf(xr[(DBASE)+10], (CV)[10], a2);             \
    a3 = fmaf(xr[(DBASE)+11], (CV)[11], a3);             \
    a0 = fmaf(xr[(DBASE)+12], (CV)[12], a0);             \
    a1 = fmaf(xr[(DBASE)+13], (CV)[13], a1);             \
    a2 = fmaf(xr[(DBASE)+14], (CV)[14], a2);             \
    a3 = fmaf(xr[(DBASE)+15], (CV)[15], a3);

__global__ __launch_bounds__(TPB, 2) void vq_main(
    const float* __restrict__ x, const float* __restrict__ emb,
    const float* __restrict__ e2n,
    float* __restrict__ out, float* __restrict__ wsum, int* __restrict__ whist)
{
    __shared__ int shist[K];
    for (int i = threadIdx.x; i < K; i += TPB) shist[i] = 0;
    __syncthreads();

    const int r = blockIdx.x * TPB + threadIdx.x;

    // row into registers (one contiguous 256B row per thread)
    float xr[D];
    {
        const float4* p = reinterpret_cast<const float4*>(x + (size_t)r * D);
        #pragma unroll
        for (int i = 0; i < D/4; ++i) {
            float4 v = p[i];
            xr[4*i+0]=v.x; xr[4*i+1]=v.y; xr[4*i+2]=v.z; xr[4*i+3]=v.w;
        }
    }

    const float* cb  = emb;    // wave-uniform codebook cursor
    const float* pe2 = e2n;    // wave-uniform e2 cursor

    float best = 3.4e38f;
    int   bi = 0;

    // Single-SGPR-buffer SMEM loop: codebook + e2 on the scalar path,
    // zero VMEM / zero LDS / zero readlane in the hot loop.
    #pragma clang loop unroll(disable)
    for (int k = 0; k < K; ++k) {
        f32x16 c0, c1, c2, c3;
        float  se2;
        asm volatile("s_load_dwordx16 %0, %1, 0x0"  : "=s"(c0) : "s"(cb));
        asm volatile("s_load_dwordx16 %0, %1, 0x40" : "=s"(c1) : "s"(cb));
        asm volatile("s_load_dwordx16 %0, %1, 0x80" : "=s"(c2) : "s"(cb));
        asm volatile("s_load_dwordx16 %0, %1, 0xc0" : "=s"(c3) : "s"(cb));
        asm volatile("s_load_dword %0, %1, 0x0"     : "=s"(se2): "s"(pe2));
        asm volatile("s_waitcnt lgkmcnt(0)" ::: "memory");
        __builtin_amdgcn_sched_barrier(0);     // rule 18: no FMA hoist above wait

        float a0=0.f, a1=0.f, a2=0.f, a3=0.f;
        ACCBUF(c0,  0)
        ACCBUF(c1, 16)
        ACCBUF(c2, 32)
        ACCBUF(c3, 48)
        float dot  = (a0+a1)+(a2+a3);
        float dist = fmaf(-2.f, dot, se2);
        if (dist < best) { best = dist; bi = k; }   // strict <: first-min

        cb  += D;
        pe2 += 1;
    }

    // epilogue: gather code from global (L2-hot), straight-through out,
    // squared-diff accumulation, index, histogram  (bit-identical to R1-5)
    float dsum = 0.f;
    {
        const float4* eq = reinterpret_cast<const float4*>(emb + (size_t)bi * D);
        float4* o = reinterpret_cast<float4*>(out + (size_t)r * D);
        #pragma unroll
        for (int i = 0; i < D/4; ++i) {
            float4 q = eq[i];
            float4 v;
            float d0,d1,d2,d3;
            d0 = q.x - xr[4*i+0]; v.x = xr[4*i+0] + d0; dsum = fmaf(d0,d0,dsum);
            d1 = q.y - xr[4*i+1]; v.y = xr[4*i+1] + d1; dsum = fmaf(d1,d1,dsum);
            d2 = q.z - xr[4*i+2]; v.z = xr[4*i+2] + d2; dsum = fmaf(d2,d2,dsum);
            d3 = q.w - xr[4*i+3]; v.w = xr[4*i+3] + d3; dsum = fmaf(d3,d3,dsum);
            o[i] = v;
        }
    }

    out[IDX_OFF + r] = (float)bi;
    atomicAdd(&shist[bi], 1);

    // wave reduction of squared-diff, one global atomic per wave
    #pragma unroll
    for (int off = 32; off > 0; off >>= 1)
        dsum += __shfl_xor(dsum, off, 64);
    if ((threadIdx.x & 63) == 0)
        atomicAdd(wsum, dsum);

    __syncthreads();
    for (int i = threadIdx.x; i < K; i += TPB)
        if (shist[i]) atomicAdd(&whist[i], shist[i]);
}

__global__ __launch_bounds__(K) void vq_finalize(
    const float* __restrict__ wsum, const int* __restrict__ whist,
    float* __restrict__ out)
{
    __shared__ float red[K];
    int t = threadIdx.x;
    float c = (float)whist[t];
    float p = c / (float)NROWS;
    red[t] = p * logf(p + 1e-10f);
    __syncthreads();
    for (int s = K/2; s > 0; s >>= 1) {
        if (t < s) red[t] += red[t+s];
        __syncthreads();
    }
    if (t == 0) {
        out[PERP_OFF] = expf(-red[0]);
        out[LOSS_OFF] = 0.25f * (wsum[0] / (float)(NROWS*D));
    }
}

extern "C" void kernel_launch(void* const* d_in, const int* in_sizes, int n_in,
                              void* d_out, int out_size, void* d_ws, size_t ws_size,
                              hipStream_t stream)
{
    const float* x   = (const float*)d_in[0];
    const float* emb = (const float*)d_in[1];
    float* out   = (float*)d_out;
    float* wsum  = (float*)d_ws;                          // 1 float @ 0
    int*   whist = (int*)((char*)d_ws + 256);             // 512 ints @ 256B
    float* e2    = (float*)((char*)d_ws + 4096);          // 512 floats @ 4096B

    hipMemsetAsync(d_ws, 0, 4096, stream);                // zero wsum + hist
    vq_norms<<<K/64, 64, 0, stream>>>(emb, e2);
    vq_main<<<NBLOCKS, TPB, 0, stream>>>(x, emb, e2, out, wsum, whist);
    vq_finalize<<<1, K, 0, stream>>>(wsum, whist, out);
}

// Round 7
// 256.113 us; speedup vs baseline: 1.0017x; 1.0017x over previous
//
#include <hip/hip_runtime.h>

#define NROWS 131072          // 64*2048
#define D 64
#define K 512
#define TPB 256
#define NBLOCKS (NROWS/TPB)   // 512 blocks -> HW can pack 2 blocks/CU

#define LOSS_OFF (NROWS*D)    // 8388608
#define PERP_OFF (LOSS_OFF+1)
#define IDX_OFF  (LOSS_OFF+2)

typedef float f32x16 __attribute__((ext_vector_type(16)));

// ws layout: [0]: float wsum; [256B]: int hist[512]; [4096B]: float e2[512]

__global__ __launch_bounds__(64) void vq_norms(
    const float* __restrict__ emb, float* __restrict__ e2)
{
    int k = blockIdx.x * 64 + threadIdx.x;   // grid 8 x 64
    const float* e = emb + (size_t)k * D;
    float s0=0.f,s1=0.f,s2=0.f,s3=0.f;
    #pragma unroll
    for (int d = 0; d < D; d += 4) {
        s0 = fmaf(e[d+0], e[d+0], s0);
        s1 = fmaf(e[d+1], e[d+1], s1);
        s2 = fmaf(e[d+2], e[d+2], s2);
        s3 = fmaf(e[d+3], e[d+3], s3);
    }
    e2[k] = (s0+s1)+(s2+s3);   // same order as rounds 1-6 (absmax 0.0)
}

// accumulate 16 elements of buf CV (d = DBASE..DBASE+15) into chains a0..a3,
// element order d ascending, chain = d%4 — bit-identical sequence to R1-R6.
#define ACCBUF(CV, DBASE)                                \
    a0 = fmaf(xr[(DBASE)+ 0], (CV)[ 0], a0);             \
    a1 = fmaf(xr[(DBASE)+ 1], (CV)[ 1], a1);             \
    a2 = fmaf(xr[(DBASE)+ 2], (CV)[ 2], a2);             \
    a3 = fmaf(xr[(DBASE)+ 3], (CV)[ 3], a3);             \
    a0 = fmaf(xr[(DBASE)+ 4], (CV)[ 4], a0);             \
    a1 = fmaf(xr[(DBASE)+ 5], (CV)[ 5], a1);             \
    a2 = fmaf(xr[(DBASE)+ 6], (CV)[ 6], a2);             \
    a3 = fmaf(xr[(DBASE)+ 7], (CV)[ 7], a3);             \
    a0 = fmaf(xr[(DBASE)+ 8], (CV)[ 8], a0);             \
    a1 = fmaf(xr[(DBASE)+ 9], (CV)[ 9], a1);             \
    a2 = fmaf(xr[(DBASE)+10], (CV)[10], a2);             \
    a3 = fmaf(xr[(DBASE)+11], (CV)[11], a3);             \
    a0 = fmaf(xr[(DBASE)+12], (CV)[12], a0);             \
    a1 = fmaf(xr[(DBASE)+13], (CV)[13], a1);             \
    a2 = fmaf(xr[(DBASE)+14], (CV)[14], a2);             \
    a3 = fmaf(xr[(DBASE)+15], (CV)[15], a3);

// ONLY change vs round 6: __launch_bounds__ min-waves 2 -> 1.
// (R1/R5 vs R2/R3/R4/R6 evidence: min-waves=1 is the only setting where the
//  allocator keeps a 64-float row in VGPRs instead of spilling to scratch.)
__global__ __launch_bounds__(TPB, 1) void vq_main(
    const float* __restrict__ x, const float* __restrict__ emb,
    const float* __restrict__ e2n,
    float* __restrict__ out, float* __restrict__ wsum, int* __restrict__ whist)
{
    __shared__ int shist[K];
    for (int i = threadIdx.x; i < K; i += TPB) shist[i] = 0;
    __syncthreads();

    const int r = blockIdx.x * TPB + threadIdx.x;

    // row into registers (one contiguous 256B row per thread)
    float xr[D];
    {
        const float4* p = reinterpret_cast<const float4*>(x + (size_t)r * D);
        #pragma unroll
        for (int i = 0; i < D/4; ++i) {
            float4 v = p[i];
            xr[4*i+0]=v.x; xr[4*i+1]=v.y; xr[4*i+2]=v.z; xr[4*i+3]=v.w;
        }
    }

    const float* cb  = emb;    // wave-uniform codebook cursor
    const float* pe2 = e2n;    // wave-uniform e2 cursor

    float best = 3.4e38f;
    int   bi = 0;

    // Single-SGPR-buffer SMEM loop: codebook + e2 on the scalar path,
    // zero VMEM / zero LDS / zero readlane in the hot loop.
    #pragma clang loop unroll(disable)
    for (int k = 0; k < K; ++k) {
        f32x16 c0, c1, c2, c3;
        float  se2;
        asm volatile("s_load_dwordx16 %0, %1, 0x0"  : "=s"(c0) : "s"(cb));
        asm volatile("s_load_dwordx16 %0, %1, 0x40" : "=s"(c1) : "s"(cb));
        asm volatile("s_load_dwordx16 %0, %1, 0x80" : "=s"(c2) : "s"(cb));
        asm volatile("s_load_dwordx16 %0, %1, 0xc0" : "=s"(c3) : "s"(cb));
        asm volatile("s_load_dword %0, %1, 0x0"     : "=s"(se2): "s"(pe2));
        asm volatile("s_waitcnt lgkmcnt(0)" ::: "memory");
        __builtin_amdgcn_sched_barrier(0);     // rule 18: no FMA hoist above wait

        float a0=0.f, a1=0.f, a2=0.f, a3=0.f;
        ACCBUF(c0,  0)
        ACCBUF(c1, 16)
        ACCBUF(c2, 32)
        ACCBUF(c3, 48)
        float dot  = (a0+a1)+(a2+a3);
        float dist = fmaf(-2.f, dot, se2);
        if (dist < best) { best = dist; bi = k; }   // strict <: first-min

        cb  += D;
        pe2 += 1;
    }

    // epilogue: gather code from global (L2-hot), straight-through out,
    // squared-diff accumulation, index, histogram  (bit-identical to R1-6)
    float dsum = 0.f;
    {
        const float4* eq = reinterpret_cast<const float4*>(emb + (size_t)bi * D);
        float4* o = reinterpret_cast<float4*>(out + (size_t)r * D);
        #pragma unroll
        for (int i = 0; i < D/4; ++i) {
            float4 q = eq[i];
            float4 v;
            float d0,d1,d2,d3;
            d0 = q.x - xr[4*i+0]; v.x = xr[4*i+0] + d0; dsum = fmaf(d0,d0,dsum);
            d1 = q.y - xr[4*i+1]; v.y = xr[4*i+1] + d1; dsum = fmaf(d1,d1,dsum);
            d2 = q.z - xr[4*i+2]; v.z = xr[4*i+2] + d2; dsum = fmaf(d2,d2,dsum);
            d3 = q.w - xr[4*i+3]; v.w = xr[4*i+3] + d3; dsum = fmaf(d3,d3,dsum);
            o[i] = v;
        }
    }

    out[IDX_OFF + r] = (float)bi;
    atomicAdd(&shist[bi], 1);

    // wave reduction of squared-diff, one global atomic per wave
    #pragma unroll
    for (int off = 32; off > 0; off >>= 1)
        dsum += __shfl_xor(dsum, off, 64);
    if ((threadIdx.x & 63) == 0)
        atomicAdd(wsum, dsum);

    __syncthreads();
    for (int i = threadIdx.x; i < K; i += TPB)
        if (shist[i]) atomicAdd(&whist[i], shist[i]);
}

__global__ __launch_bounds__(K) void vq_finalize(
    const float* __restrict__ wsum, const int* __restrict__ whist,
    float* __restrict__ out)
{
    __shared__ float red[K];
    int t = threadIdx.x;
    float c = (float)whist[t];
    float p = c / (float)NROWS;
    red[t] = p * logf(p + 1e-10f);
    __syncthreads();
    for (int s = K/2; s > 0; s >>= 1) {
        if (t < s) red[t] += red[t+s];
        __syncthreads();
    }
    if (t == 0) {
        out[PERP_OFF] = expf(-red[0]);
        out[LOSS_OFF] = 0.25f * (wsum[0] / (float)(NROWS*D));
    }
}

extern "C" void kernel_launch(void* const* d_in, const int* in_sizes, int n_in,
                              void* d_out, int out_size, void* d_ws, size_t ws_size,
                              hipStream_t stream)
{
    const float* x   = (const float*)d_in[0];
    const float* emb = (const float*)d_in[1];
    float* out   = (float*)d_out;
    float* wsum  = (float*)d_ws;                          // 1 float @ 0
    int*   whist = (int*)((char*)d_ws + 256);             // 512 ints @ 256B
    float* e2    = (float*)((char*)d_ws + 4096);          // 512 floats @ 4096B

    hipMemsetAsync(d_ws, 0, 4096, stream);                // zero wsum + hist
    vq_norms<<<K/64, 64, 0, stream>>>(emb, e2);
    vq_main<<<NBLOCKS, TPB, 0, stream>>>(x, emb, e2, out, wsum, whist);
    vq_finalize<<<1, K, 0, stream>>>(wsum, whist, out);
}

// Round 8
// 109.507 us; speedup vs baseline: 2.3428x; 2.3388x over previous
//
#include <hip/hip_runtime.h>

#define NROWS 131072          // 64*2048
#define D 64
#define K 512
#define TPB 256
#define RPB 128               // rows per block (4 waves x 32 rows)
#define NBLK (NROWS/RPB)      // 1024

#define LOSS_OFF (NROWS*D)    // 8388608
#define PERP_OFF (LOSS_OFF+1)
#define IDX_OFF  (LOSS_OFF+2)

typedef short  s16x8 __attribute__((ext_vector_type(8)));   // 8 bf16 (4 VGPR)
typedef float  f32x4 __attribute__((ext_vector_type(4)));   // MFMA acc

// ws: [0] f32 wsum | [256B] int hist[512] | [4096B] f32 e2[512] | [8192B] bfrag 196608B

// exact 3-way bf16 split of 8 floats (mask-truncate: hi+mid+lo = top 24 mantissa bits)
__device__ __forceinline__ void split8(float4 a, float4 b,
                                       s16x8* h8, s16x8* m8, s16x8* l8)
{
    float xf[8] = {a.x,a.y,a.z,a.w,b.x,b.y,b.z,b.w};
    short hh[8], mm[8], ll[8];
    #pragma unroll
    for (int j = 0; j < 8; ++j) {
        float x = xf[j];
        unsigned uh = __float_as_uint(x) & 0xFFFF0000u;
        float rh = x - __uint_as_float(uh);            // exact
        unsigned um = __float_as_uint(rh) & 0xFFFF0000u;
        float rm = rh - __uint_as_float(um);           // exact
        unsigned ul = __float_as_uint(rm) & 0xFFFF0000u;
        hh[j] = (short)(uh >> 16);
        mm[j] = (short)(um >> 16);
        ll[j] = (short)(ul >> 16);
    }
    *h8 = (s16x8){hh[0],hh[1],hh[2],hh[3],hh[4],hh[5],hh[6],hh[7]};
    *m8 = (s16x8){mm[0],mm[1],mm[2],mm[3],mm[4],mm[5],mm[6],mm[7]};
    *l8 = (s16x8){ll[0],ll[1],ll[2],ll[3],ll[4],ll[5],ll[6],ll[7]};
}

// prep: pack codebook splits into exact MFMA B-fragment order + e2 norms
__global__ __launch_bounds__(64) void vq_prep(
    const float* __restrict__ emb, float* __restrict__ e2, s16x8* __restrict__ bfrag)
{
    const int ct = blockIdx.x, l = threadIdx.x;      // 32 blocks x 64
    const int q = l >> 4, r16 = l & 15;
    const int code = ct*16 + r16;
    const float4* e4 = reinterpret_cast<const float4*>(emb + (size_t)code * D);
    #pragma unroll
    for (int s = 0; s < 2; ++s) {
        float4 f0 = e4[q*2 + s*8];
        float4 f1 = e4[q*2 + s*8 + 1];
        s16x8 h, m, lo;
        split8(f0, f1, &h, &m, &lo);
        bfrag[(ct*6 + 0 + s)*64 + l] = h;    // c2s = c*2+s, c=0
        bfrag[(ct*6 + 2 + s)*64 + l] = m;    // c=1
        bfrag[(ct*6 + 4 + s)*64 + l] = lo;   // c=2
    }
    if (l < 16) {
        const float* e = emb + (size_t)(ct*16 + l) * D;
        float s0=0.f,s1=0.f,s2=0.f,s3=0.f;
        #pragma unroll
        for (int d = 0; d < D; d += 4) {
            s0 = fmaf(e[d+0], e[d+0], s0);
            s1 = fmaf(e[d+1], e[d+1], s1);
            s2 = fmaf(e[d+2], e[d+2], s2);
            s3 = fmaf(e[d+3], e[d+3], s3);
        }
        e2[ct*16 + l] = (s0+s1)+(s2+s3);
    }
}

#define MFMA(ACC, AV, BV) \
    ACC = __builtin_amdgcn_mfma_f32_16x16x32_bf16((AV), (BV), ACC, 0, 0, 0)

__global__ __launch_bounds__(TPB, 1) void vq_main(
    const float* __restrict__ x, const float* __restrict__ emb,
    const float* __restrict__ e2g, const s16x8* __restrict__ bfrag,
    float* __restrict__ out, float* __restrict__ wsum, int* __restrict__ whist)
{
    __shared__ float4 sx[RPB*17];    // 128 rows, padded stride 17 float4 (272B)
    __shared__ int    sidx[RPB];
    __shared__ int    shist[K];

    const int t = threadIdx.x;
    for (int i = t; i < K; i += TPB) shist[i] = 0;

    // stage 128 rows coalesced into padded LDS
    const float4* xin4 = reinterpret_cast<const float4*>(x) + (size_t)blockIdx.x * (RPB*16);
    for (int g = t; g < RPB*16; g += TPB)
        sx[(g >> 4)*17 + (g & 15)] = xin4[g];
    __syncthreads();

    const int l = t & 63, w = t >> 6;
    const int q = l >> 4, r16 = l & 15;
    const int wbase = w * 32;

    // A fragments: [mt][chunk][kstep], row = wbase+mt*16+r16, k = q*8+j+32*s
    s16x8 Af[2][3][2];
    #pragma unroll
    for (int mt = 0; mt < 2; ++mt) {
        #pragma unroll
        for (int s = 0; s < 2; ++s) {
            int rl = wbase + mt*16 + r16;
            float4 f0 = sx[rl*17 + q*2 + s*8];
            float4 f1 = sx[rl*17 + q*2 + s*8 + 1];
            split8(f0, f1, &Af[mt][0][s], &Af[mt][1][s], &Af[mt][2][s]);
        }
    }

    float bestd[2][4];
    int   besti[2][4];
    #pragma unroll
    for (int mt = 0; mt < 2; ++mt)
        #pragma unroll
        for (int g = 0; g < 4; ++g) { bestd[mt][g] = 3.4e38f; besti[mt][g] = 0; }

    const s16x8* bbase = bfrag + l;

    for (int ct = 0; ct < 32; ++ct) {
        const float e2v = e2g[(ct << 4) + r16];
        const s16x8* bp = bbase + ct*6*64;
        s16x8 b00 = bp[0*64], b01 = bp[1*64];   // hi  chunk, s=0/1
        s16x8 b10 = bp[2*64], b11 = bp[3*64];   // mid chunk
        s16x8 b20 = bp[4*64], b21 = bp[5*64];   // lo  chunk

        f32x4 acc00 = {0.f,0.f,0.f,0.f}, acc10 = {0.f,0.f,0.f,0.f};
        f32x4 acc01 = {0.f,0.f,0.f,0.f}, acc11 = {0.f,0.f,0.f,0.f};

        // 6 chunk-pairs: g0 = {hh, mh, lh}, g1 = {hm, hl, mm}; round-robin 4 accs
        // pair 0
        MFMA(acc00, Af[0][0][0], b00); MFMA(acc10, Af[1][0][0], b00);
        MFMA(acc01, Af[0][0][0], b10); MFMA(acc11, Af[1][0][0], b10);
        MFMA(acc00, Af[0][0][1], b01); MFMA(acc10, Af[1][0][1], b01);
        MFMA(acc01, Af[0][0][1], b11); MFMA(acc11, Af[1][0][1], b11);
        // pair 1
        MFMA(acc00, Af[0][1][0], b00); MFMA(acc10, Af[1][1][0], b00);
        MFMA(acc01, Af[0][0][0], b20); MFMA(acc11, Af[1][0][0], b20);
        MFMA(acc00, Af[0][1][1], b01); MFMA(acc10, Af[1][1][1], b01);
        MFMA(acc01, Af[0][0][1], b21); MFMA(acc11, Af[1][0][1], b21);
        // pair 2
        MFMA(acc00, Af[0][2][0], b00); MFMA(acc10, Af[1][2][0], b00);
        MFMA(acc01, Af[0][1][0], b10); MFMA(acc11, Af[1][1][0], b10);
        MFMA(acc00, Af[0][2][1], b01); MFMA(acc10, Af[1][2][1], b01);
        MFMA(acc01, Af[0][1][1], b11); MFMA(acc11, Af[1][1][1], b11);

        const int col = (ct << 4) + r16;
        #pragma unroll
        for (int g = 0; g < 4; ++g) {
            float dot0 = acc00[g] + acc01[g];
            float dst0 = fmaf(-2.f, dot0, e2v);
            if (dst0 < bestd[0][g]) { bestd[0][g] = dst0; besti[0][g] = col; }
            float dot1 = acc10[g] + acc11[g];
            float dst1 = fmaf(-2.f, dot1, e2v);
            if (dst1 < bestd[1][g]) { bestd[1][g] = dst1; besti[1][g] = col; }
        }
    }

    // cross-lane argmin over the 16 cols held by lanes sharing q (bits 0-3)
    #pragma unroll
    for (int mask = 1; mask <= 8; mask <<= 1) {
        #pragma unroll
        for (int mt = 0; mt < 2; ++mt)
            #pragma unroll
            for (int g = 0; g < 4; ++g) {
                float od = __shfl_xor(bestd[mt][g], mask, 64);
                int   oi = __shfl_xor(besti[mt][g], mask, 64);
                if (od < bestd[mt][g] ||
                    (od == bestd[mt][g] && oi < besti[mt][g])) {
                    bestd[mt][g] = od; besti[mt][g] = oi;
                }
            }
    }
    if (r16 == 0) {
        #pragma unroll
        for (int mt = 0; mt < 2; ++mt)
            #pragma unroll
            for (int g = 0; g < 4; ++g)
                sidx[wbase + mt*16 + q*4 + g] = besti[mt][g];
    }
    __syncthreads();

    // fused epilogue: 2 threads per row, 32 elems each (x from LDS, e from L2)
    const int row = t >> 1, half = t & 1;
    const int grow = blockIdx.x * RPB + row;
    const int bi = sidx[row];
    float dsum = 0.f;
    {
        const float4* eq = reinterpret_cast<const float4*>(emb + (size_t)bi * D) + half*8;
        float4* o = reinterpret_cast<float4*>(out + (size_t)grow * D) + half*8;
        #pragma unroll
        for (int i = 0; i < 8; ++i) {
            float4 xv = sx[row*17 + half*8 + i];
            float4 qv = eq[i];
            float4 v;
            float d0,d1,d2,d3;
            d0 = qv.x - xv.x; v.x = xv.x + d0; dsum = fmaf(d0,d0,dsum);
            d1 = qv.y - xv.y; v.y = xv.y + d1; dsum = fmaf(d1,d1,dsum);
            d2 = qv.z - xv.z; v.z = xv.z + d2; dsum = fmaf(d2,d2,dsum);
            d3 = qv.w - xv.w; v.w = xv.w + d3; dsum = fmaf(d3,d3,dsum);
            o[i] = v;
        }
    }
    if (half == 0) {
        out[IDX_OFF + grow] = (float)bi;
        atomicAdd(&shist[bi], 1);
    }

    #pragma unroll
    for (int off = 32; off > 0; off >>= 1)
        dsum += __shfl_xor(dsum, off, 64);
    if ((t & 63) == 0)
        atomicAdd(wsum, dsum);

    __syncthreads();
    for (int i = t; i < K; i += TPB)
        if (shist[i]) atomicAdd(&whist[i], shist[i]);
}

__global__ __launch_bounds__(K) void vq_finalize(
    const float* __restrict__ wsum, const int* __restrict__ whist,
    float* __restrict__ out)
{
    __shared__ float red[K];
    int t = threadIdx.x;
    float c = (float)whist[t];
    float p = c / (float)NROWS;
    red[t] = p * logf(p + 1e-10f);
    __syncthreads();
    for (int s = K/2; s > 0; s >>= 1) {
        if (t < s) red[t] += red[t+s];
        __syncthreads();
    }
    if (t == 0) {
        out[PERP_OFF] = expf(-red[0]);
        out[LOSS_OFF] = 0.25f * (wsum[0] / (float)(NROWS*D));
    }
}

extern "C" void kernel_launch(void* const* d_in, const int* in_sizes, int n_in,
                              void* d_out, int out_size, void* d_ws, size_t ws_size,
                              hipStream_t stream)
{
    const float* x   = (const float*)d_in[0];
    const float* emb = (const float*)d_in[1];
    float* out   = (float*)d_out;
    float* wsum  = (float*)d_ws;                           // @0
    int*   whist = (int*)((char*)d_ws + 256);              // @256B
    float* e2    = (float*)((char*)d_ws + 4096);           // @4096B
    s16x8* bfrag = (s16x8*)((char*)d_ws + 8192);           // @8192B, 196608B

    hipMemsetAsync(d_ws, 0, 4096, stream);                 // zero wsum + hist
    vq_prep<<<32, 64, 0, stream>>>(emb, e2, bfrag);
    vq_main<<<NBLK, TPB, 0, stream>>>(x, emb, e2, bfrag, out, wsum, whist);
    vq_finalize<<<1, K, 0, stream>>>(wsum, whist, out);
}

// Round 9
// 106.353 us; speedup vs baseline: 2.4122x; 1.0297x over previous
//
#include <hip/hip_runtime.h>

#define NROWS 131072          // 64*2048
#define D 64
#define K 512
#define TPB 256
#define RPB 128               // rows per block (4 waves x 32 rows)
#define NBLK (NROWS/RPB)      // 1024

#define LOSS_OFF (NROWS*D)    // 8388608
#define PERP_OFF (LOSS_OFF+1)
#define IDX_OFF  (LOSS_OFF+2)

typedef short  s16x8 __attribute__((ext_vector_type(8)));   // 8 bf16 (4 VGPR)
typedef float  f32x4 __attribute__((ext_vector_type(4)));   // MFMA acc

// ws: [0] f32 wsum | [256B] int hist[512] | [4096B] f32 e2[512] | [8192B] bfrag 196608B

// exact 3-way bf16 split of 8 floats (mask-truncate: hi+mid+lo = top 24 mantissa bits)
__device__ __forceinline__ void split8(float4 a, float4 b,
                                       s16x8* h8, s16x8* m8, s16x8* l8)
{
    float xf[8] = {a.x,a.y,a.z,a.w,b.x,b.y,b.z,b.w};
    short hh[8], mm[8], ll[8];
    #pragma unroll
    for (int j = 0; j < 8; ++j) {
        float x = xf[j];
        unsigned uh = __float_as_uint(x) & 0xFFFF0000u;
        float rh = x - __uint_as_float(uh);            // exact
        unsigned um = __float_as_uint(rh) & 0xFFFF0000u;
        float rm = rh - __uint_as_float(um);           // exact
        unsigned ul = __float_as_uint(rm) & 0xFFFF0000u;
        hh[j] = (short)(uh >> 16);
        mm[j] = (short)(um >> 16);
        ll[j] = (short)(ul >> 16);
    }
    *h8 = (s16x8){hh[0],hh[1],hh[2],hh[3],hh[4],hh[5],hh[6],hh[7]};
    *m8 = (s16x8){mm[0],mm[1],mm[2],mm[3],mm[4],mm[5],mm[6],mm[7]};
    *l8 = (s16x8){ll[0],ll[1],ll[2],ll[3],ll[4],ll[5],ll[6],ll[7]};
}

// prep: pack codebook splits into exact MFMA B-fragment order + e2 norms
__global__ __launch_bounds__(64) void vq_prep(
    const float* __restrict__ emb, float* __restrict__ e2, s16x8* __restrict__ bfrag)
{
    const int ct = blockIdx.x, l = threadIdx.x;      // 32 blocks x 64
    const int q = l >> 4, r16 = l & 15;
    const int code = ct*16 + r16;
    const float4* e4 = reinterpret_cast<const float4*>(emb + (size_t)code * D);
    #pragma unroll
    for (int s = 0; s < 2; ++s) {
        float4 f0 = e4[q*2 + s*8];
        float4 f1 = e4[q*2 + s*8 + 1];
        s16x8 h, m, lo;
        split8(f0, f1, &h, &m, &lo);
        bfrag[(ct*6 + 0 + s)*64 + l] = h;    // c2s = c*2+s, c=0
        bfrag[(ct*6 + 2 + s)*64 + l] = m;    // c=1
        bfrag[(ct*6 + 4 + s)*64 + l] = lo;   // c=2
    }
    if (l < 16) {
        const float* e = emb + (size_t)(ct*16 + l) * D;
        float s0=0.f,s1=0.f,s2=0.f,s3=0.f;
        #pragma unroll
        for (int d = 0; d < D; d += 4) {
            s0 = fmaf(e[d+0], e[d+0], s0);
            s1 = fmaf(e[d+1], e[d+1], s1);
            s2 = fmaf(e[d+2], e[d+2], s2);
            s3 = fmaf(e[d+3], e[d+3], s3);
        }
        e2[ct*16 + l] = (s0+s1)+(s2+s3);
    }
}

#define MFMA(ACC, AV, BV) \
    ACC = __builtin_amdgcn_mfma_f32_16x16x32_bf16((AV), (BV), ACC, 0, 0, 0)

// load B-fragment set for tile CT into named regs (7 loads, stay in flight)
#define LOADB(B00,B01,B10,B11,B20,B21,E2V, CT) do {                 \
    const s16x8* _bp = bbase + (size_t)(CT)*6*64;                   \
    B00 = _bp[0*64]; B01 = _bp[1*64];                               \
    B10 = _bp[2*64]; B11 = _bp[3*64];                               \
    B20 = _bp[4*64]; B21 = _bp[5*64];                               \
    E2V = e2g[((CT) << 4) + r16];                                   \
} while (0)

// 24 MFMAs + per-tile argmin on B-set (identical math/order to round 8)
#define COMPUTE(B00,B01,B10,B11,B20,B21,E2V, CT) do {               \
    f32x4 acc00 = {0.f,0.f,0.f,0.f}, acc10 = {0.f,0.f,0.f,0.f};     \
    f32x4 acc01 = {0.f,0.f,0.f,0.f}, acc11 = {0.f,0.f,0.f,0.f};     \
    MFMA(acc00, Af[0][0][0], B00); MFMA(acc10, Af[1][0][0], B00);   \
    MFMA(acc01, Af[0][0][0], B10); MFMA(acc11, Af[1][0][0], B10);   \
    MFMA(acc00, Af[0][0][1], B01); MFMA(acc10, Af[1][0][1], B01);   \
    MFMA(acc01, Af[0][0][1], B11); MFMA(acc11, Af[1][0][1], B11);   \
    MFMA(acc00, Af[0][1][0], B00); MFMA(acc10, Af[1][1][0], B00);   \
    MFMA(acc01, Af[0][0][0], B20); MFMA(acc11, Af[1][0][0], B20);   \
    MFMA(acc00, Af[0][1][1], B01); MFMA(acc10, Af[1][1][1], B01);   \
    MFMA(acc01, Af[0][0][1], B21); MFMA(acc11, Af[1][0][1], B21);   \
    MFMA(acc00, Af[0][2][0], B00); MFMA(acc10, Af[1][2][0], B00);   \
    MFMA(acc01, Af[0][1][0], B10); MFMA(acc11, Af[1][1][0], B10);   \
    MFMA(acc00, Af[0][2][1], B01); MFMA(acc10, Af[1][2][1], B01);   \
    MFMA(acc01, Af[0][1][1], B11); MFMA(acc11, Af[1][1][1], B11);   \
    const int _col = ((CT) << 4) + r16;                             \
    _Pragma("unroll")                                               \
    for (int g = 0; g < 4; ++g) {                                   \
        float dot0 = acc00[g] + acc01[g];                           \
        float dst0 = fmaf(-2.f, dot0, E2V);                         \
        if (dst0 < bestd[0][g]) { bestd[0][g] = dst0; besti[0][g] = _col; } \
        float dot1 = acc10[g] + acc11[g];                           \
        float dst1 = fmaf(-2.f, dot1, E2V);                         \
        if (dst1 < bestd[1][g]) { bestd[1][g] = dst1; besti[1][g] = _col; } \
    }                                                               \
} while (0)

__global__ __launch_bounds__(TPB, 1) void vq_main(
    const float* __restrict__ x, const float* __restrict__ emb,
    const float* __restrict__ e2g, const s16x8* __restrict__ bfrag,
    float* __restrict__ out, float* __restrict__ wsum, int* __restrict__ whist)
{
    __shared__ float4 sx[RPB*17];    // 128 rows, padded stride 17 float4 (272B)
    __shared__ int    sidx[RPB];
    __shared__ int    shist[K];

    const int t = threadIdx.x;
    for (int i = t; i < K; i += TPB) shist[i] = 0;

    // stage 128 rows coalesced into padded LDS
    const float4* xin4 = reinterpret_cast<const float4*>(x) + (size_t)blockIdx.x * (RPB*16);
    for (int g = t; g < RPB*16; g += TPB)
        sx[(g >> 4)*17 + (g & 15)] = xin4[g];
    __syncthreads();

    const int l = t & 63, w = t >> 6;
    const int q = l >> 4, r16 = l & 15;
    const int wbase = w * 32;

    // A fragments: [mt][chunk][kstep], row = wbase+mt*16+r16, k = q*8+j+32*s
    s16x8 Af[2][3][2];
    #pragma unroll
    for (int mt = 0; mt < 2; ++mt) {
        #pragma unroll
        for (int s = 0; s < 2; ++s) {
            int rl = wbase + mt*16 + r16;
            float4 f0 = sx[rl*17 + q*2 + s*8];
            float4 f1 = sx[rl*17 + q*2 + s*8 + 1];
            split8(f0, f1, &Af[mt][0][s], &Af[mt][1][s], &Af[mt][2][s]);
        }
    }

    float bestd[2][4];
    int   besti[2][4];
    #pragma unroll
    for (int mt = 0; mt < 2; ++mt)
        #pragma unroll
        for (int g = 0; g < 4; ++g) { bestd[mt][g] = 3.4e38f; besti[mt][g] = 0; }

    const s16x8* bbase = bfrag + l;

    // double-buffered B stream: P = even tiles, Q = odd tiles, distance-2 prefetch
    s16x8 p00,p01,p10,p11,p20,p21; float pe2;
    s16x8 q00,q01,q10,q11,q20,q21; float qe2;
    LOADB(p00,p01,p10,p11,p20,p21,pe2, 0);
    LOADB(q00,q01,q10,q11,q20,q21,qe2, 1);

    #pragma clang loop unroll(disable)
    for (int ct = 0; ct < 32; ct += 2) {
        COMPUTE(p00,p01,p10,p11,p20,p21,pe2, ct);
        LOADB(p00,p01,p10,p11,p20,p21,pe2, (ct + 2) & 31);   // in flight across Q's compute
        COMPUTE(q00,q01,q10,q11,q20,q21,qe2, ct + 1);
        LOADB(q00,q01,q10,q11,q20,q21,qe2, (ct + 3) & 31);   // in flight across next P
    }

    // cross-lane argmin over the 16 cols held by lanes sharing q (bits 0-3)
    #pragma unroll
    for (int mask = 1; mask <= 8; mask <<= 1) {
        #pragma unroll
        for (int mt = 0; mt < 2; ++mt)
            #pragma unroll
            for (int g = 0; g < 4; ++g) {
                float od = __shfl_xor(bestd[mt][g], mask, 64);
                int   oi = __shfl_xor(besti[mt][g], mask, 64);
                if (od < bestd[mt][g] ||
                    (od == bestd[mt][g] && oi < besti[mt][g])) {
                    bestd[mt][g] = od; besti[mt][g] = oi;
                }
            }
    }
    if (r16 == 0) {
        #pragma unroll
        for (int mt = 0; mt < 2; ++mt)
            #pragma unroll
            for (int g = 0; g < 4; ++g)
                sidx[wbase + mt*16 + q*4 + g] = besti[mt][g];
    }
    __syncthreads();

    // fused epilogue: 2 threads per row, 32 elems each (x from LDS, e from L2)
    const int row = t >> 1, half = t & 1;
    const int grow = blockIdx.x * RPB + row;
    const int bi = sidx[row];
    float dsum = 0.f;
    {
        const float4* eq = reinterpret_cast<const float4*>(emb + (size_t)bi * D) + half*8;
        float4* o = reinterpret_cast<float4*>(out + (size_t)grow * D) + half*8;
        #pragma unroll
        for (int i = 0; i < 8; ++i) {
            float4 xv = sx[row*17 + half*8 + i];
            float4 qv = eq[i];
            float4 v;
            float d0,d1,d2,d3;
            d0 = qv.x - xv.x; v.x = xv.x + d0; dsum = fmaf(d0,d0,dsum);
            d1 = qv.y - xv.y; v.y = xv.y + d1; dsum = fmaf(d1,d1,dsum);
            d2 = qv.z - xv.z; v.z = xv.z + d2; dsum = fmaf(d2,d2,dsum);
            d3 = qv.w - xv.w; v.w = xv.w + d3; dsum = fmaf(d3,d3,dsum);
            o[i] = v;
        }
    }
    if (half == 0) {
        out[IDX_OFF + grow] = (float)bi;
        atomicAdd(&shist[bi], 1);
    }

    #pragma unroll
    for (int off = 32; off > 0; off >>= 1)
        dsum += __shfl_xor(dsum, off, 64);
    if ((t & 63) == 0)
        atomicAdd(wsum, dsum);

    __syncthreads();
    for (int i = t; i < K; i += TPB)
        if (shist[i]) atomicAdd(&whist[i], shist[i]);
}

__global__ __launch_bounds__(K) void vq_finalize(
    const float* __restrict__ wsum, const int* __restrict__ whist,
    float* __restrict__ out)
{
    __shared__ float red[K];
    int t = threadIdx.x;
    float c = (float)whist[t];
    float p = c / (float)NROWS;
    red[t] = p * logf(p + 1e-10f);
    __syncthreads();
    for (int s = K/2; s > 0; s >>= 1) {
        if (t < s) red[t] += red[t+s];
        __syncthreads();
    }
    if (t == 0) {
        out[PERP_OFF] = expf(-red[0]);
        out[LOSS_OFF] = 0.25f * (wsum[0] / (float)(NROWS*D));
    }
}

extern "C" void kernel_launch(void* const* d_in, const int* in_sizes, int n_in,
                              void* d_out, int out_size, void* d_ws, size_t ws_size,
                              hipStream_t stream)
{
    const float* x   = (const float*)d_in[0];
    const float* emb = (const float*)d_in[1];
    float* out   = (float*)d_out;
    float* wsum  = (float*)d_ws;                           // @0
    int*   whist = (int*)((char*)d_ws + 256);              // @256B
    float* e2    = (float*)((char*)d_ws + 4096);           // @4096B
    s16x8* bfrag = (s16x8*)((char*)d_ws + 8192);           // @8192B, 196608B

    hipMemsetAsync(d_ws, 0, 4096, stream);                 // zero wsum + hist
    vq_prep<<<32, 64, 0, stream>>>(emb, e2, bfrag);
    vq_main<<<NBLK, TPB, 0, stream>>>(x, emb, e2, bfrag, out, wsum, whist);
    vq_finalize<<<1, K, 0, stream>>>(wsum, whist, out);
}

// Round 10
// 93.826 us; speedup vs baseline: 2.7343x; 1.1335x over previous
//
#include <hip/hip_runtime.h>

#define NROWS 131072          // 64*2048
#define D 64
#define K 512
#define TPB 256
#define RPB 128               // rows per block (4 waves x 32 rows)
#define NBLK (NROWS/RPB)      // 1024

#define LOSS_OFF (NROWS*D)    // 8388608
#define PERP_OFF (LOSS_OFF+1)
#define IDX_OFF  (LOSS_OFF+2)

typedef short  s16x8 __attribute__((ext_vector_type(8)));   // 8 bf16 (4 VGPR)
typedef float  f32x4 __attribute__((ext_vector_type(4)));   // MFMA acc

// ws: [0] f32 wsum | [256B] int hist[512] | [4096B] f32 e2[512] | [8192B] bfrag 196608B

// exact 3-way bf16 split of 8 floats (mask-truncate: hi+mid+lo = top 24 mantissa bits)
__device__ __forceinline__ void split8(float4 a, float4 b,
                                       s16x8* h8, s16x8* m8, s16x8* l8)
{
    float xf[8] = {a.x,a.y,a.z,a.w,b.x,b.y,b.z,b.w};
    short hh[8], mm[8], ll[8];
    #pragma unroll
    for (int j = 0; j < 8; ++j) {
        float x = xf[j];
        unsigned uh = __float_as_uint(x) & 0xFFFF0000u;
        float rh = x - __uint_as_float(uh);            // exact
        unsigned um = __float_as_uint(rh) & 0xFFFF0000u;
        float rm = rh - __uint_as_float(um);           // exact
        unsigned ul = __float_as_uint(rm) & 0xFFFF0000u;
        hh[j] = (short)(uh >> 16);
        mm[j] = (short)(um >> 16);
        ll[j] = (short)(ul >> 16);
    }
    *h8 = (s16x8){hh[0],hh[1],hh[2],hh[3],hh[4],hh[5],hh[6],hh[7]};
    *m8 = (s16x8){mm[0],mm[1],mm[2],mm[3],mm[4],mm[5],mm[6],mm[7]};
    *l8 = (s16x8){ll[0],ll[1],ll[2],ll[3],ll[4],ll[5],ll[6],ll[7]};
}

// prep: pack (-2*codebook) splits into MFMA B-fragment order + e2 norms.
// (-2x is exact: sign flip + exponent+1 commute with bf16 mask-truncation.)
__global__ __launch_bounds__(64) void vq_prep(
    const float* __restrict__ emb, float* __restrict__ e2, s16x8* __restrict__ bfrag)
{
    const int ct = blockIdx.x, l = threadIdx.x;      // 32 blocks x 64
    const int q = l >> 4, r16 = l & 15;
    const int code = ct*16 + r16;
    const float4* e4 = reinterpret_cast<const float4*>(emb + (size_t)code * D);
    #pragma unroll
    for (int s = 0; s < 2; ++s) {
        float4 f0 = e4[q*2 + s*8];
        float4 f1 = e4[q*2 + s*8 + 1];
        float4 g0 = {-2.f*f0.x, -2.f*f0.y, -2.f*f0.z, -2.f*f0.w};
        float4 g1 = {-2.f*f1.x, -2.f*f1.y, -2.f*f1.z, -2.f*f1.w};
        s16x8 h, m, lo;
        split8(g0, g1, &h, &m, &lo);
        bfrag[(ct*6 + 0 + s)*64 + l] = h;    // hi chunk, kstep s
        bfrag[(ct*6 + 2 + s)*64 + l] = m;    // mid
        bfrag[(ct*6 + 4 + s)*64 + l] = lo;   // lo
    }
    if (l < 16) {
        const float* e = emb + (size_t)(ct*16 + l) * D;
        float s0=0.f,s1=0.f,s2=0.f,s3=0.f;
        #pragma unroll
        for (int d = 0; d < D; d += 4) {
            s0 = fmaf(e[d+0], e[d+0], s0);
            s1 = fmaf(e[d+1], e[d+1], s1);
            s2 = fmaf(e[d+2], e[d+2], s2);
            s3 = fmaf(e[d+3], e[d+3], s3);
        }
        e2[ct*16 + l] = (s0+s1)+(s2+s3);
    }
}

#define MFMA(ACC, AV, BV) \
    ACC = __builtin_amdgcn_mfma_f32_16x16x32_bf16((AV), (BV), ACC, 0, 0, 0)
#define MFMA_I(ACC, AV, BV, CI) \
    ACC = __builtin_amdgcn_mfma_f32_16x16x32_bf16((AV), (BV), (CI), 0, 0, 0)

// load B-fragment set for tile CT into named regs (stay in flight)
#define LOADB(B00,B01,B10,B11,B20,B21,E2V, CT) do {                 \
    const s16x8* _bp = bbase + (size_t)(CT)*6*64;                   \
    B00 = _bp[0*64]; B01 = _bp[1*64];                               \
    B10 = _bp[2*64]; B11 = _bp[3*64];                               \
    B20 = _bp[4*64]; B21 = _bp[5*64];                               \
    E2V = e2g[((CT) << 4) + r16];                                   \
} while (0)

// 24 MFMAs for one tile into acc set {S00,S01,S10,S11}.
// S00/S10 chains seeded with e2 splat; dist = S00[g]+S01[g] (= e2 - 2*dot,
// B pre-scaled by -2).
#define TILE_MFMA(S00,S01,S10,S11, B00,B01,B10,B11,B20,B21, E2V) do {        \
    f32x4 _ci = {(E2V),(E2V),(E2V),(E2V)};                                   \
    MFMA_I(S00, Af[0][0][0], B00, _ci);   MFMA_I(S10, Af[1][0][0], B00, _ci);\
    MFMA_I(S01, Af[0][0][0], B10, zero4); MFMA_I(S11, Af[1][0][0], B10, zero4);\
    MFMA(S00, Af[0][0][1], B01); MFMA(S10, Af[1][0][1], B01);                \
    MFMA(S01, Af[0][0][1], B11); MFMA(S11, Af[1][0][1], B11);                \
    MFMA(S00, Af[0][1][0], B00); MFMA(S10, Af[1][1][0], B00);                \
    MFMA(S01, Af[0][0][0], B20); MFMA(S11, Af[1][0][0], B20);                \
    MFMA(S00, Af[0][1][1], B01); MFMA(S10, Af[1][1][1], B01);                \
    MFMA(S01, Af[0][0][1], B21); MFMA(S11, Af[1][0][1], B21);                \
    MFMA(S00, Af[0][2][0], B00); MFMA(S10, Af[1][2][0], B00);                \
    MFMA(S01, Af[0][1][0], B10); MFMA(S11, Af[1][1][0], B10);                \
    MFMA(S00, Af[0][2][1], B01); MFMA(S10, Af[1][2][1], B01);                \
    MFMA(S01, Af[0][1][1], B11); MFMA(S11, Af[1][1][1], B11);                \
} while (0)

// running argmin over one finished acc set (independent of current MFMAs)
#define TILE_ARGMIN(S00,S01,S10,S11, CT) do {                                \
    const int _col = ((CT) << 4) + r16;                                      \
    _Pragma("unroll")                                                        \
    for (int g = 0; g < 4; ++g) {                                            \
        float dst0 = S00[g] + S01[g];                                        \
        if (dst0 < bestd[0][g]) { bestd[0][g] = dst0; besti[0][g] = _col; }  \
        float dst1 = S10[g] + S11[g];                                        \
        if (dst1 < bestd[1][g]) { bestd[1][g] = dst1; besti[1][g] = _col; }  \
    }                                                                        \
} while (0)

__global__ __launch_bounds__(TPB, 1) void vq_main(
    const float* __restrict__ x, const float* __restrict__ emb,
    const float* __restrict__ e2g, const s16x8* __restrict__ bfrag,
    float* __restrict__ out, float* __restrict__ wsum, int* __restrict__ whist)
{
    __shared__ float4 sx[RPB*17];    // 128 rows, padded stride 17 float4
    __shared__ int    sidx[RPB];
    __shared__ int    shist[K];

    const int t = threadIdx.x;
    for (int i = t; i < K; i += TPB) shist[i] = 0;

    // stage 128 rows coalesced into padded LDS
    const float4* xin4 = reinterpret_cast<const float4*>(x) + (size_t)blockIdx.x * (RPB*16);
    for (int g = t; g < RPB*16; g += TPB)
        sx[(g >> 4)*17 + (g & 15)] = xin4[g];
    __syncthreads();

    const int l = t & 63, w = t >> 6;
    const int q = l >> 4, r16 = l & 15;
    const int wbase = w * 32;

    // A fragments: [mt][chunk][kstep], row = wbase+mt*16+r16, k = q*8+j+32*s
    s16x8 Af[2][3][2];
    #pragma unroll
    for (int mt = 0; mt < 2; ++mt) {
        #pragma unroll
        for (int s = 0; s < 2; ++s) {
            int rl = wbase + mt*16 + r16;
            float4 f0 = sx[rl*17 + q*2 + s*8];
            float4 f1 = sx[rl*17 + q*2 + s*8 + 1];
            split8(f0, f1, &Af[mt][0][s], &Af[mt][1][s], &Af[mt][2][s]);
        }
    }

    float bestd[2][4];
    int   besti[2][4];
    #pragma unroll
    for (int mt = 0; mt < 2; ++mt)
        #pragma unroll
        for (int g = 0; g < 4; ++g) { bestd[mt][g] = 3.4e38f; besti[mt][g] = 0; }

    const s16x8* bbase = bfrag + l;
    const f32x4 zero4 = {0.f,0.f,0.f,0.f};

    // B double-buffer (P even / Q odd tiles) + acc double-buffer (E even / O odd)
    s16x8 p00,p01,p10,p11,p20,p21; float pe2;
    s16x8 q00,q01,q10,q11,q20,q21; float qe2;
    f32x4 eA,eB,eC,eD;   // even-tile acc set
    f32x4 oA,oB,oC,oD;   // odd-tile acc set

    LOADB(p00,p01,p10,p11,p20,p21,pe2, 0);
    LOADB(q00,q01,q10,q11,q20,q21,qe2, 1);
    TILE_MFMA(eA,eB,eC,eD, p00,p01,p10,p11,p20,p21, pe2);
    LOADB(p00,p01,p10,p11,p20,p21,pe2, 2);

    #pragma clang loop unroll(disable)
    for (int ct = 1; ct < 31; ct += 2) {
        // MFMA odd tile ct while argmin of even tile ct-1 runs on the VALU pipe
        TILE_MFMA(oA,oB,oC,oD, q00,q01,q10,q11,q20,q21, qe2);
        LOADB(q00,q01,q10,q11,q20,q21,qe2, ct + 2);
        TILE_ARGMIN(eA,eB,eC,eD, ct - 1);
        // MFMA even tile ct+1 while argmin of odd tile ct runs
        TILE_MFMA(eA,eB,eC,eD, p00,p01,p10,p11,p20,p21, pe2);
        LOADB(p00,p01,p10,p11,p20,p21,pe2, (ct + 3) & 31);  // 32->0 dead load
        TILE_ARGMIN(oA,oB,oC,oD, ct);
    }
    TILE_MFMA(oA,oB,oC,oD, q00,q01,q10,q11,q20,q21, qe2);   // tile 31
    TILE_ARGMIN(eA,eB,eC,eD, 30);
    TILE_ARGMIN(oA,oB,oC,oD, 31);

    // cross-lane argmin over the 16 cols held by lanes sharing q (bits 0-3)
    #pragma unroll
    for (int mask = 1; mask <= 8; mask <<= 1) {
        #pragma unroll
        for (int mt = 0; mt < 2; ++mt)
            #pragma unroll
            for (int g = 0; g < 4; ++g) {
                float od = __shfl_xor(bestd[mt][g], mask, 64);
                int   oi = __shfl_xor(besti[mt][g], mask, 64);
                if (od < bestd[mt][g] ||
                    (od == bestd[mt][g] && oi < besti[mt][g])) {
                    bestd[mt][g] = od; besti[mt][g] = oi;
                }
            }
    }
    if (r16 == 0) {
        #pragma unroll
        for (int mt = 0; mt < 2; ++mt)
            #pragma unroll
            for (int g = 0; g < 4; ++g)
                sidx[wbase + mt*16 + q*4 + g] = besti[mt][g];
    }
    __syncthreads();

    // fused epilogue: 2 threads per row, 32 elems each (x from LDS, e from L2)
    const int row = t >> 1, half = t & 1;
    const int grow = blockIdx.x * RPB + row;
    const int bi = sidx[row];
    float dsum = 0.f;
    {
        const float4* eq = reinterpret_cast<const float4*>(emb + (size_t)bi * D) + half*8;
        float4* o = reinterpret_cast<float4*>(out + (size_t)grow * D) + half*8;
        #pragma unroll
        for (int i = 0; i < 8; ++i) {
            float4 xv = sx[row*17 + half*8 + i];
            float4 qv = eq[i];
            float4 v;
            float d0,d1,d2,d3;
            d0 = qv.x - xv.x; v.x = xv.x + d0; dsum = fmaf(d0,d0,dsum);
            d1 = qv.y - xv.y; v.y = xv.y + d1; dsum = fmaf(d1,d1,dsum);
            d2 = qv.z - xv.z; v.z = xv.z + d2; dsum = fmaf(d2,d2,dsum);
            d3 = qv.w - xv.w; v.w = xv.w + d3; dsum = fmaf(d3,d3,dsum);
            o[i] = v;
        }
    }
    if (half == 0) {
        out[IDX_OFF + grow] = (float)bi;
        atomicAdd(&shist[bi], 1);
    }

    #pragma unroll
    for (int off = 32; off > 0; off >>= 1)
        dsum += __shfl_xor(dsum, off, 64);
    if ((t & 63) == 0)
        atomicAdd(wsum, dsum);

    __syncthreads();
    for (int i = t; i < K; i += TPB)
        if (shist[i]) atomicAdd(&whist[i], shist[i]);
}

__global__ __launch_bounds__(K) void vq_finalize(
    const float* __restrict__ wsum, const int* __restrict__ whist,
    float* __restrict__ out)
{
    __shared__ float red[K];
    int t = threadIdx.x;
    float c = (float)whist[t];
    float p = c / (float)NROWS;
    red[t] = p * logf(p + 1e-10f);
    __syncthreads();
    for (int s = K/2; s > 0; s >>= 1) {
        if (t < s) red[t] += red[t+s];
        __syncthreads();
    }
    if (t == 0) {
        out[PERP_OFF] = expf(-red[0]);
        out[LOSS_OFF] = 0.25f * (wsum[0] / (float)(NROWS*D));
    }
}

extern "C" void kernel_launch(void* const* d_in, const int* in_sizes, int n_in,
                              void* d_out, int out_size, void* d_ws, size_t ws_size,
                              hipStream_t stream)
{
    const float* x   = (const float*)d_in[0];
    const float* emb = (const float*)d_in[1];
    float* out   = (float*)d_out;
    float* wsum  = (float*)d_ws;                           // @0
    int*   whist = (int*)((char*)d_ws + 256);              // @256B
    float* e2    = (float*)((char*)d_ws + 4096);           // @4096B
    s16x8* bfrag = (s16x8*)((char*)d_ws + 8192);           // @8192B, 196608B

    hipMemsetAsync(d_ws, 0, 4096, stream);                 // zero wsum + hist
    vq_prep<<<32, 64, 0, stream>>>(emb, e2, bfrag);
    vq_main<<<NBLK, TPB, 0, stream>>>(x, emb, e2, bfrag, out, wsum, whist);
    vq_finalize<<<1, K, 0, stream>>>(wsum, whist, out);
}